// Round 1
// baseline (233.361 us; speedup 1.0000x reference)
//
#include <hip/hip_runtime.h>

#define DIM 128
#define LN_EPS 1e-5f

typedef __attribute__((ext_vector_type(8))) short bf16x8;
typedef __attribute__((ext_vector_type(4))) float f32x4;

static __device__ __forceinline__ unsigned short f2bf(float f) {
    unsigned int u = __builtin_bit_cast(unsigned int, f);
    u += 0x7fffu + ((u >> 16) & 1u);  // round-to-nearest-even
    return (unsigned short)(u >> 16);
}
static __device__ __forceinline__ float bf2f_lo(unsigned int u) {
    return __builtin_bit_cast(float, u << 16);
}
static __device__ __forceinline__ float bf2f_hi(unsigned int u) {
    return __builtin_bit_cast(float, u & 0xffff0000u);
}

// --------------------- fused: W transpose+cvt, degree count
__global__ __launch_bounds__(256) void wt_count_kernel(const float* __restrict__ W1,
                                                       const float* __restrict__ W2,
                                                       unsigned short* __restrict__ Wt1,
                                                       unsigned short* __restrict__ Wt2,
                                                       const int* __restrict__ dst,
                                                       int* __restrict__ counts, int E) {
    int b = blockIdx.x;
    if (b < 128) {
        int elem = b * 256 + threadIdx.x;  // [0, 32768)
        int which = elem >> 14;
        int rest = elem & 16383;
        int c = rest >> 7;
        int k = rest & 127;
        const float* W = which ? W2 : W1;
        unsigned short* Wt = which ? Wt2 : Wt1;
        Wt[c * 128 + k] = f2bf(W[k * 128 + c]);
    } else {
        int e = (b - 128) * 256 + threadIdx.x;
        if (e < E) atomicAdd(&counts[dst[e]], 1);
    }
}

// ------------------------------------------------- scan pass 1 (+dinv compute)
__global__ __launch_bounds__(256) void scan1_kernel(const int* __restrict__ counts,
                                                    int* __restrict__ tmp,
                                                    int* __restrict__ bsums,
                                                    float* __restrict__ dinv, int n) {
    __shared__ int ts[256];
    int tid = threadIdx.x;
    int base = blockIdx.x * 1024 + tid * 4;
    int v[4];
#pragma unroll
    for (int j = 0; j < 4; ++j) {
        int i = base + j;
        v[j] = (i < n) ? counts[i] : 0;
        if (i < n) dinv[i] = rsqrtf((float)(v[j] + 1));  // +1 self-loop
    }
    int s = v[0] + v[1] + v[2] + v[3];
    ts[tid] = s;
    __syncthreads();
    for (int off = 1; off < 256; off <<= 1) {
        int t2 = (tid >= off) ? ts[tid - off] : 0;
        __syncthreads();
        ts[tid] += t2;
        __syncthreads();
    }
    int excl = ts[tid] - s;
    int pre = excl;
#pragma unroll
    for (int j = 0; j < 4; ++j) {
        int i = base + j;
        if (i < n) tmp[i] = pre;
        pre += v[j];
    }
    if (tid == 255) bsums[blockIdx.x] = ts[255];
}

// ------------------- scan pass 2+3 merged
__global__ __launch_bounds__(256) void scan3_kernel(const int* __restrict__ tmp,
                                                    const int* __restrict__ bsums,
                                                    int* __restrict__ rowptr,
                                                    int* __restrict__ cursor,
                                                    int n, int E, int nb) {
    __shared__ int s_add;
    if (threadIdx.x < 64) {
        int lane = threadIdx.x;
        int v = (lane < nb) ? bsums[lane] : 0;
        int x = v;
#pragma unroll
        for (int off = 1; off < 64; off <<= 1) {
            int y = __shfl_up(x, off);
            if (lane >= off) x += y;
        }
        int excl = x - v;
        int mine = __builtin_amdgcn_readlane(excl, blockIdx.x);
        if (lane == 0) s_add = mine;
    }
    __syncthreads();
    int add = s_add;
    int base = blockIdx.x * 1024 + threadIdx.x * 4;
#pragma unroll
    for (int j = 0; j < 4; ++j) {
        int i = base + j;
        if (i < n) {
            int val = tmp[i] + add;
            rowptr[i] = val;
            cursor[i] = val;
        }
    }
    if (blockIdx.x == 0 && threadIdx.x == 0) rowptr[n] = E;
}

// ------------- merged dispatch: layer-1 MFMA GEMM (blocks [0,gG)) + CSR fill
// (blocks [gG, gG+gE)). The two are independent; gemm blocks go first so MFMA
// compute overlaps the fill's atomic/scatter latency instead of serializing.
__global__ __launch_bounds__(256) void gemm1_fill_kernel(const float* __restrict__ A,
                                                         const unsigned short* __restrict__ Bt,
                                                         const float* __restrict__ dinv,
                                                         unsigned short* __restrict__ H,
                                                         int n, int ntiles, int gG,
                                                         const int* __restrict__ src,
                                                         const int* __restrict__ dst,
                                                         int* __restrict__ cursor,
                                                         unsigned short* __restrict__ colsrc,
                                                         int E) {
    __shared__ unsigned short Wlds[128 * 136];
    if (blockIdx.x >= gG) {
        // ---- CSR fill part ----
        int e = (blockIdx.x - gG) * 256 + threadIdx.x;
        if (e < E) {
            int p = atomicAdd(&cursor[dst[e]], 1);
            colsrc[p] = (unsigned short)src[e];
        }
        return;
    }
    // ---- layer-1 GEMM part (identical numerics to previous version) ----
    for (int u = threadIdx.x; u < 2048; u += 256) {
        int row = u >> 4;
        int sub = u & 15;
        *(bf16x8*)&Wlds[row * 136 + sub * 8] = *(const bf16x8*)(Bt + row * 128 + sub * 8);
    }
    __syncthreads();

    int wid = threadIdx.x >> 6;
    int lane = threadIdx.x & 63;
    int tile = blockIdx.x * 4 + wid;
    if (tile >= ntiles) tile = ntiles - 1;
    int r0 = tile * 16;
    int mrow = lane & 15;
    int kgrp = lane >> 4;

    int arow_i = r0 + mrow;
    if (arow_i > n - 1) arow_i = n - 1;
    const float* arow = A + (size_t)arow_i * DIM + kgrp * 8;

    f32x4 acc[8];
#pragma unroll
    for (int t = 0; t < 8; ++t) acc[t] = (f32x4){0.f, 0.f, 0.f, 0.f};

#pragma unroll
    for (int kc = 0; kc < 4; ++kc) {
        float4 v0 = *(const float4*)(arow + kc * 32);
        float4 v1 = *(const float4*)(arow + kc * 32 + 4);
        bf16x8 af;
        af[0] = (short)f2bf(v0.x); af[1] = (short)f2bf(v0.y);
        af[2] = (short)f2bf(v0.z); af[3] = (short)f2bf(v0.w);
        af[4] = (short)f2bf(v1.x); af[5] = (short)f2bf(v1.y);
        af[6] = (short)f2bf(v1.z); af[7] = (short)f2bf(v1.w);
#pragma unroll
        for (int t = 0; t < 8; ++t) {
            bf16x8 bfv = *(const bf16x8*)&Wlds[(t * 16 + mrow) * 136 + kc * 32 + kgrp * 8];
            acc[t] = __builtin_amdgcn_mfma_f32_16x16x32_bf16(af, bfv, acc[t], 0, 0, 0);
        }
    }

    float dv[4];
#pragma unroll
    for (int reg = 0; reg < 4; ++reg) {
        int rr = r0 + kgrp * 4 + reg;
        dv[reg] = (rr < n) ? dinv[rr] : 0.f;
    }
#pragma unroll
    for (int t = 0; t < 8; ++t) {
#pragma unroll
        for (int reg = 0; reg < 4; ++reg) {
            int row = r0 + kgrp * 4 + reg;
            if (row < n) {
                int col = t * 16 + mrow;
                H[(size_t)row * DIM + col] = f2bf(acc[t][reg] * dv[reg]);
            }
        }
    }
}

// ------------- FUSED: gather + bias + LN + ReLU  ->  layer-2 GEMM (MFMA)
// Each wave owns a 16-node MFMA tile. Gather phase: 4 rounds x 4 nodes/wave,
// 16 lanes per node, uint4 (16B) row-slice loads -> 16 rows (16 KB) in flight
// per chunk per wave. LN result is written bf16 into a per-wave LDS tile
// (per-column accumulation order identical to the previous two-kernel path,
// so layer-2 numerics are bit-identical). MFMA phase then computes
// H2 = (Y1 @ W2) * dinv directly — the Y1 global round-trip is eliminated.
__global__ __launch_bounds__(256) void gather_gemm_kernel(const int* __restrict__ rowptr,
                                                          const unsigned short* __restrict__ colsrc,
                                                          const uint4* __restrict__ H4,
                                                          const float* __restrict__ dinv,
                                                          const float* __restrict__ bias,
                                                          const float* __restrict__ gamma,
                                                          const float* __restrict__ beta,
                                                          const unsigned short* __restrict__ Wt2,
                                                          unsigned short* __restrict__ H2,
                                                          int n, int ntiles) {
    __shared__ unsigned short Wlds[128 * 136];        // 34.8 KB: W2^T
    __shared__ unsigned short Tl[4][16][136];         // 17.4 KB: per-wave Y1 tiles
    for (int u = threadIdx.x; u < 2048; u += 256) {
        int row = u >> 4;
        int sub = u & 15;
        *(bf16x8*)&Wlds[row * 136 + sub * 8] = *(const bf16x8*)(Wt2 + row * 128 + sub * 8);
    }
    __syncthreads();

    int wid = threadIdx.x >> 6;
    int lane = threadIdx.x & 63;
    int tile = blockIdx.x * 4 + wid;
    if (tile >= ntiles) tile = ntiles - 1;
    int r0 = tile * 16;
    int grp = lane >> 4;   // which of 4 nodes this round
    int gl = lane & 15;    // lane within node: covers cols [gl*8, gl*8+8)

    float4 bb0 = ((const float4*)bias)[gl * 2];
    float4 bb1 = ((const float4*)bias)[gl * 2 + 1];
    float4 gg0 = ((const float4*)gamma)[gl * 2];
    float4 gg1 = ((const float4*)gamma)[gl * 2 + 1];
    float4 be0 = ((const float4*)beta)[gl * 2];
    float4 be1 = ((const float4*)beta)[gl * 2 + 1];

    for (int t = 0; t < 4; ++t) {
        int r = r0 + t * 4 + grp;
        int rc = (r < n) ? r : (n - 1);
        float di = dinv[rc];
        uint4 su = H4[(size_t)rc * 16 + gl];   // self-loop term (pre-scaled)
        float a0 = bf2f_lo(su.x), a1 = bf2f_hi(su.x);
        float a2 = bf2f_lo(su.y), a3 = bf2f_hi(su.y);
        float a4 = bf2f_lo(su.z), a5 = bf2f_hi(su.z);
        float a6 = bf2f_lo(su.w), a7 = bf2f_hi(su.w);

        int p0 = rowptr[rc];
        int p1 = rowptr[rc + 1];
        int deg = p1 - p0;
        int m = max(deg, __shfl_xor(deg, 16));
        m = max(m, __shfl_xor(m, 32));
        int nch = (m + 15) >> 4;

        for (int c = 0; c < nch; ++c) {
            int cb = c * 16;
            int gi = p0 + cb + gl;
            gi = gi < p1 ? gi : p1 - 1;        // clamp: valid duplicate
            int idxv = (int)colsrc[gi];        // this node's 16 edges across its 16 lanes

            uint4 h[16];
#pragma unroll
            for (int j = 0; j < 16; ++j) {
                int s = __shfl(idxv, grp * 16 + j);   // broadcast within own group
                h[j] = H4[(size_t)s * 16 + gl];
            }
#pragma unroll
            for (int j = 0; j < 16; ++j) {
                bool act = (cb + j < deg);            // group-uniform; cndmask
                a0 += act ? bf2f_lo(h[j].x) : 0.f;
                a1 += act ? bf2f_hi(h[j].x) : 0.f;
                a2 += act ? bf2f_lo(h[j].y) : 0.f;
                a3 += act ? bf2f_hi(h[j].y) : 0.f;
                a4 += act ? bf2f_lo(h[j].z) : 0.f;
                a5 += act ? bf2f_hi(h[j].z) : 0.f;
                a6 += act ? bf2f_lo(h[j].w) : 0.f;
                a7 += act ? bf2f_hi(h[j].w) : 0.f;
            }
        }

        float v0 = a0 * di + bb0.x;
        float v1 = a1 * di + bb0.y;
        float v2 = a2 * di + bb0.z;
        float v3 = a3 * di + bb0.w;
        float v4 = a4 * di + bb1.x;
        float v5 = a5 * di + bb1.y;
        float v6 = a6 * di + bb1.z;
        float v7 = a7 * di + bb1.w;

        float s1 = v0 + v1 + v2 + v3 + v4 + v5 + v6 + v7;
        float s2 = v0 * v0 + v1 * v1 + v2 * v2 + v3 * v3 +
                   v4 * v4 + v5 * v5 + v6 * v6 + v7 * v7;
#pragma unroll
        for (int off = 8; off > 0; off >>= 1) {   // reduce within 16-lane group
            s1 += __shfl_xor(s1, off);
            s2 += __shfl_xor(s2, off);
        }
        float mu = s1 * (1.f / 128.f);
        float var = s2 * (1.f / 128.f) - mu * mu;
        float rstd = rsqrtf(var + LN_EPS);

        float o0 = fmaxf((v0 - mu) * rstd * gg0.x + be0.x, 0.f);
        float o1 = fmaxf((v1 - mu) * rstd * gg0.y + be0.y, 0.f);
        float o2 = fmaxf((v2 - mu) * rstd * gg0.z + be0.z, 0.f);
        float o3 = fmaxf((v3 - mu) * rstd * gg0.w + be0.w, 0.f);
        float o4 = fmaxf((v4 - mu) * rstd * gg1.x + be1.x, 0.f);
        float o5 = fmaxf((v5 - mu) * rstd * gg1.y + be1.y, 0.f);
        float o6 = fmaxf((v6 - mu) * rstd * gg1.z + be1.z, 0.f);
        float o7 = fmaxf((v7 - mu) * rstd * gg1.w + be1.w, 0.f);

        bf16x8 pk;
        pk[0] = (short)f2bf(o0); pk[1] = (short)f2bf(o1);
        pk[2] = (short)f2bf(o2); pk[3] = (short)f2bf(o3);
        pk[4] = (short)f2bf(o4); pk[5] = (short)f2bf(o5);
        pk[6] = (short)f2bf(o6); pk[7] = (short)f2bf(o7);
        *(bf16x8*)&Tl[wid][t * 4 + grp][gl * 8] = pk;   // 272B row stride: 16B aligned
    }

    __syncthreads();   // (per-wave tile; barrier is belt-and-braces, cost ~0)

    // ---- layer-2 MFMA: acc = Tl(16x128 bf16) @ W2, then *dinv -> H2 ----
    int mrow = lane & 15;
    int kg = lane >> 4;
    f32x4 acc[8];
#pragma unroll
    for (int t = 0; t < 8; ++t) acc[t] = (f32x4){0.f, 0.f, 0.f, 0.f};

#pragma unroll
    for (int kc = 0; kc < 4; ++kc) {
        bf16x8 af = *(const bf16x8*)&Tl[wid][mrow][kc * 32 + kg * 8];
#pragma unroll
        for (int t = 0; t < 8; ++t) {
            bf16x8 bfv = *(const bf16x8*)&Wlds[(t * 16 + mrow) * 136 + kc * 32 + kg * 8];
            acc[t] = __builtin_amdgcn_mfma_f32_16x16x32_bf16(af, bfv, acc[t], 0, 0, 0);
        }
    }

    float dv[4];
#pragma unroll
    for (int reg = 0; reg < 4; ++reg) {
        int rr = r0 + kg * 4 + reg;
        dv[reg] = (rr < n) ? dinv[rr] : 0.f;
    }
#pragma unroll
    for (int t = 0; t < 8; ++t) {
#pragma unroll
        for (int reg = 0; reg < 4; ++reg) {
            int row = r0 + kg * 4 + reg;
            if (row < n) {
                int col = t * 16 + mrow;
                H2[(size_t)row * DIM + col] = f2bf(acc[t][reg] * dv[reg]);
            }
        }
    }
}

// ------------- DUAL-NODE gather + bias + LN (final layer, fp32 out)
__global__ __launch_bounds__(256) void gather_ln_kernel(const int* __restrict__ rowptr,
                                                        const unsigned short* __restrict__ colsrc,
                                                        const uint2* __restrict__ H2,
                                                        const float* __restrict__ dinv,
                                                        const float* __restrict__ bias,
                                                        const float* __restrict__ gamma,
                                                        const float* __restrict__ beta,
                                                        uint2* __restrict__ out_bf,
                                                        float* __restrict__ out_f,
                                                        int n, int relu) {
    int wid = threadIdx.x >> 6;
    int lane = threadIdx.x & 63;
    int half = lane >> 5;           // 0 or 1: which node
    int hl = lane & 31;             // lane within half
    int r = blockIdx.x * 8 + wid * 2 + half;
    int valid = (r < n);
    int rc = valid ? r : (n - 1);

    float di = dinv[rc];
    float4 bb = ((const float4*)bias)[hl];
    float4 gg = ((const float4*)gamma)[hl];
    float4 be = ((const float4*)beta)[hl];

    uint2 su = H2[(size_t)rc * 32 + hl];   // self-loop term (pre-scaled)
    float a0 = bf2f_lo(su.x), a1 = bf2f_hi(su.x);
    float a2 = bf2f_lo(su.y), a3 = bf2f_hi(su.y);

    int p0 = rowptr[rc];
    int p1 = rowptr[rc + 1];
    int deg = p1 - p0;
    int maxd = max(deg, __shfl_xor(deg, 32));
    int nchunks = (maxd + 15) >> 4;
    int hbase = half << 5;

    for (int c = 0; c < nchunks; ++c) {
        int cbase = c * 16;
        int gi = p0 + cbase + hl;
        gi = gi < p1 ? gi : p1 - 1;        // clamp: valid duplicate
        int idxv = (int)colsrc[gi];

        uint2 h[16];
#pragma unroll
        for (int j = 0; j < 16; ++j) {
            int s = __shfl(idxv, hbase + j);
            h[j] = H2[(size_t)s * 32 + hl];
        }
#pragma unroll
        for (int j = 0; j < 16; ++j) {
            bool act = (cbase + j < deg);
            a0 += act ? bf2f_lo(h[j].x) : 0.f;
            a1 += act ? bf2f_hi(h[j].x) : 0.f;
            a2 += act ? bf2f_lo(h[j].y) : 0.f;
            a3 += act ? bf2f_hi(h[j].y) : 0.f;
        }
    }

    float v0 = a0 * di + bb.x;
    float v1 = a1 * di + bb.y;
    float v2 = a2 * di + bb.z;
    float v3 = a3 * di + bb.w;

    float s1 = v0 + v1 + v2 + v3;
    float s2 = v0 * v0 + v1 * v1 + v2 * v2 + v3 * v3;
#pragma unroll
    for (int off = 16; off > 0; off >>= 1) {
        s1 += __shfl_xor(s1, off);
        s2 += __shfl_xor(s2, off);
    }
    float mu = s1 * (1.f / 128.f);
    float var = s2 * (1.f / 128.f) - mu * mu;
    float rstd = rsqrtf(var + LN_EPS);

    float o0 = (v0 - mu) * rstd * gg.x + be.x;
    float o1 = (v1 - mu) * rstd * gg.y + be.y;
    float o2 = (v2 - mu) * rstd * gg.z + be.z;
    float o3 = (v3 - mu) * rstd * gg.w + be.w;
    if (relu) {
        o0 = fmaxf(o0, 0.f); o1 = fmaxf(o1, 0.f);
        o2 = fmaxf(o2, 0.f); o3 = fmaxf(o3, 0.f);
    }
    if (valid) {
        if (out_bf) {
            uint2 pk;
            pk.x = (unsigned int)f2bf(o0) | ((unsigned int)f2bf(o1) << 16);
            pk.y = (unsigned int)f2bf(o2) | ((unsigned int)f2bf(o3) << 16);
            out_bf[(size_t)r * 32 + hl] = pk;
        } else {
            ((float4*)out_f)[(size_t)r * 32 + hl] = make_float4(o0, o1, o2, o3);
        }
    }
}

// =============================================================================
extern "C" void kernel_launch(void* const* d_in, const int* in_sizes, int n_in,
                              void* d_out, int out_size, void* d_ws, size_t ws_size,
                              hipStream_t stream) {
    const float* x   = (const float*)d_in[0];
    const int*   ei  = (const int*)d_in[1];
    const float* W1  = (const float*)d_in[2];
    const float* b1  = (const float*)d_in[3];
    const float* g1  = (const float*)d_in[4];
    const float* be1 = (const float*)d_in[5];
    const float* W2  = (const float*)d_in[6];
    const float* b2  = (const float*)d_in[7];
    const float* g2  = (const float*)d_in[8];
    const float* be2 = (const float*)d_in[9];

    int n = in_sizes[0] / DIM;   // 50000
    int E = in_sizes[1] / 2;     // 600000
    const int* src = ei;
    const int* dst = ei + E;

    char* wp = (char*)d_ws;
    auto alloc = [&](size_t bytes) {
        void* p = (void*)wp;
        wp += (bytes + 255) & ~(size_t)255;
        return p;
    };
    float*          dinv   = (float*)alloc((size_t)n * 4);
    int*            counts = (int*)alloc((size_t)n * 4);
    int*            tmp    = (int*)alloc((size_t)n * 4);
    int*            rowptr = (int*)alloc((size_t)(n + 1) * 4);
    int*            cursor = (int*)alloc((size_t)n * 4);
    int*            bsums  = (int*)alloc(64 * 4);
    unsigned short* colsrc = (unsigned short*)alloc((size_t)E * 2);
    unsigned short* Wt1    = (unsigned short*)alloc(128 * 128 * 2);
    unsigned short* Wt2    = (unsigned short*)alloc(128 * 128 * 2);
    unsigned short* H      = (unsigned short*)alloc((size_t)n * DIM * 2);
    unsigned short* H2     = (unsigned short*)alloc((size_t)n * DIM * 2);

    hipMemsetAsync(counts, 0, (size_t)n * 4, stream);

    // --- W transpose + degree count (one dispatch) ---
    int gE = (E + 255) / 256;
    wt_count_kernel<<<128 + gE, 256, 0, stream>>>(W1, W2, Wt1, Wt2, dst, counts, E);

    // --- CSR build ---
    int nb1 = (n + 1023) / 1024;  // 49 for n=50000 (must be <= 64)
    scan1_kernel<<<nb1, 256, 0, stream>>>(counts, tmp, bsums, dinv, n);
    scan3_kernel<<<nb1, 256, 0, stream>>>(tmp, bsums, rowptr, cursor, n, E, nb1);

    int ntiles = (n + 15) / 16;
    int gG = (ntiles + 3) / 4;

    // --- layer-1 GEMM overlapped with CSR fill (independent work, one dispatch) ---
    gemm1_fill_kernel<<<gG + gE, 256, 0, stream>>>(x, Wt1, dinv, H, n, ntiles, gG,
                                                   src, dst, cursor, colsrc, E);

    // --- gather+LN+ReLU fused with layer-2 GEMM (Y1 never hits global) ---
    gather_gemm_kernel<<<gG, 256, 0, stream>>>(rowptr, colsrc, (const uint4*)H, dinv,
                                               b1, g1, be1, Wt2, H2, n, ntiles);

    // --- final gather + LN -> fp32 out ---
    int gA = (n + 7) / 8;
    gather_ln_kernel<<<gA, 256, 0, stream>>>(rowptr, colsrc, (const uint2*)H2, dinv,
                                             b2, g2, be2, nullptr, (float*)d_out, n, 0);
}